// Round 16
// baseline (64.700 us; speedup 1.0000x reference)
//
#include <hip/hip_runtime.h>
#include <hip/hip_bf16.h>
#include <math.h>

#define S_LEN 2048
#define E_DIM 1024
#define NHEAD 8
#define DH 128
#define E3 3072

typedef short bf16x8 __attribute__((ext_vector_type(8)));
typedef short bf16x4 __attribute__((ext_vector_type(4)));
typedef float f32x4 __attribute__((ext_vector_type(4)));
typedef float f32x16 __attribute__((ext_vector_type(16)));

#define MFMA3216(a,b,c) __builtin_amdgcn_mfma_f32_32x32x16_bf16(a,b,c,0,0,0)
#define Z16 {0.f,0.f,0.f,0.f,0.f,0.f,0.f,0.f,0.f,0.f,0.f,0.f,0.f,0.f,0.f,0.f}
#define CROW(r) (((r)&3) + 8*((r)>>2))

__device__ __forceinline__ unsigned short f2bf(float f){
  union{float f; unsigned u;} x; x.f = f;
  unsigned r = x.u + 0x7FFF + ((x.u>>16)&1);
  return (unsigned short)(r>>16);
}

__device__ __forceinline__ unsigned cvtpk(float lo, float hi){
  unsigned r;
  asm("v_cvt_pk_bf16_f32 %0, %1, %2" : "=v"(r) : "v"(lo), "v"(hi));
  return r;
}

__device__ __forceinline__ float logsigf(float x){
  return fminf(x, 0.f) - log1pf(expf(-fabsf(x)));
}

typedef const __attribute__((address_space(1))) unsigned int* gas1_t;
typedef __attribute__((address_space(3))) unsigned int* las3_t;
__device__ __forceinline__ void stage16(const ushort* g, ushort* l){
  __builtin_amdgcn_global_load_lds((gas1_t)(const void*)g, (las3_t)(void*)l, 16, 0, 0);
}

// ------ Kernel A: r9's proven gates (acc[64] butterfly) + fused V^T --------
__global__ __launch_bounds__(256) void gates_qk(
    const float* __restrict__ q, const float* __restrict__ k, const float* __restrict__ v,
    const float* __restrict__ igw, const float* __restrict__ igb,
    const float* __restrict__ fgw, const float* __restrict__ fgb,
    float* __restrict__ ig_out, float* __restrict__ lsf_out,
    ushort* __restrict__ qbo, ushort* __restrict__ kbo, ushort* __restrict__ vto){
  const int t0 = blockIdx.x*4;
  const int tid = threadIdx.x;
  const int lane = tid & 63, wv = tid >> 6;
  float acc[64];
  #pragma unroll
  for (int a=0;a<64;++a) acc[a]=0.f;
  const float sc = 0.08838834764831845f;  // 1/sqrt(128)
  #pragma unroll
  for (int step=0; step<3; ++step){
    const float* src = (step==0)? q : ((step==1)? k : v);
    float4 in4[4];
    #pragma unroll
    for (int r=0;r<4;++r) in4[r] = ((const float4*)src)[(size_t)(t0+r)*256 + tid];
    if (step==0){
      #pragma unroll
      for (int r=0;r<4;++r){
        ushort4 o; o.x=f2bf(in4[r].x*sc); o.y=f2bf(in4[r].y*sc);
        o.z=f2bf(in4[r].z*sc); o.w=f2bf(in4[r].w*sc);
        ((ushort4*)qbo)[(size_t)(t0+r)*256 + tid] = o;
      }
    } else if (step==1){
      #pragma unroll
      for (int r=0;r<4;++r){
        ushort4 o; o.x=f2bf(in4[r].x); o.y=f2bf(in4[r].y);
        o.z=f2bf(in4[r].z); o.w=f2bf(in4[r].w);
        ((ushort4*)kbo)[(size_t)(t0+r)*256 + tid] = o;
      }
    } else {
      #pragma unroll
      for (int c=0;c<4;++c){
        ushort4 ov;
        ov.x = f2bf(((const float*)&in4[0])[c]);
        ov.y = f2bf(((const float*)&in4[1])[c]);
        ov.z = f2bf(((const float*)&in4[2])[c]);
        ov.w = f2bf(((const float*)&in4[3])[c]);
        *(ushort4*)(vto + (size_t)(tid*4+c)*S_LEN + t0) = ov;
      }
    }
    const int wj = step*256 + tid;
    #pragma unroll
    for (int o=0;o<8;++o){
      float4 wI = ((const float4*)igw)[o*768 + wj];
      float4 wF = ((const float4*)fgw)[o*768 + wj];
      #pragma unroll
      for (int r=0;r<4;++r){
        acc[o*4+r]    = fmaf(in4[r].x, wI.x, acc[o*4+r]);
        acc[o*4+r]    = fmaf(in4[r].y, wI.y, acc[o*4+r]);
        acc[o*4+r]    = fmaf(in4[r].z, wI.z, acc[o*4+r]);
        acc[o*4+r]    = fmaf(in4[r].w, wI.w, acc[o*4+r]);
        acc[32+o*4+r] = fmaf(in4[r].x, wF.x, acc[32+o*4+r]);
        acc[32+o*4+r] = fmaf(in4[r].y, wF.y, acc[32+o*4+r]);
        acc[32+o*4+r] = fmaf(in4[r].z, wF.z, acc[32+o*4+r]);
        acc[32+o*4+r] = fmaf(in4[r].w, wF.w, acc[32+o*4+r]);
      }
    }
  }
  int cnt = 32;
  #pragma unroll
  for (int s=0; s<6; ++s){
    const bool hib = (lane >> s) & 1;
    #pragma unroll
    for (int a=0; a<32; ++a){
      if (a < cnt){
        float sent = hib ? acc[a] : acc[a+cnt];
        float got = __shfl_xor(sent, 1<<s, 64);
        acc[a] = (hib ? acc[a+cnt] : acc[a]) + got;
      }
    }
    cnt >>= 1;
  }
  __shared__ float red[4][64];
  red[wv][lane] = acc[0];
  __syncthreads();
  if (tid < 64){
    float tot = red[0][tid]+red[1][tid]+red[2][tid]+red[3][tid];
    int a = (int)(__brev((unsigned)tid) >> 26);   // bitrev6
    int f = a >> 5, o = (a>>2)&7, r = a&3;
    int t = t0 + r;
    if (f==0) ig_out[o*S_LEN + t] = tot + igb[o];
    else      lsf_out[o*S_LEN + t] = logsigf(tot + fgb[o]);
  }
}

// ---------------- Kernel B: per-head scans ---------------------------------
__global__ __launch_bounds__(256) void scan_kernel(
    const float* __restrict__ ig, const float* __restrict__ lsf,
    float* __restrict__ cs_out, float* __restrict__ M_out, float* __restrict__ m_out){
  const int h = blockIdx.x;
  const int tid = threadIdx.x;
  __shared__ float tt[256];
  const int base = tid*8;
  const float* src = lsf + h*S_LEN;
  float loc[8]; float tot = 0.f;
  #pragma unroll
  for (int i=0;i<8;++i){ tot += src[base+i]; loc[i]=tot; }
  tt[tid]=tot; __syncthreads();
  for (int off=1; off<256; off<<=1){
    float add = (tid>=off)? tt[tid-off] : 0.f;
    __syncthreads();
    tt[tid] += add;
    __syncthreads();
  }
  const float excl = tt[tid] - tot;
  float csv[8];
  #pragma unroll
  for (int i=0;i<8;++i){ csv[i] = excl + loc[i]; cs_out[h*S_LEN+base+i]=csv[i]; }
  const float* igp = ig + h*S_LEN;
  float mloc[8], mval[8]; float mtot = -INFINITY;
  #pragma unroll
  for (int i=0;i<8;++i){
    float m = igp[base+i] - csv[i];
    mval[i] = m;
    mtot = fmaxf(mtot, m);
    mloc[i] = mtot;
  }
  __syncthreads();
  tt[tid]=mtot; __syncthreads();
  for (int off=1; off<256; off<<=1){
    float add = (tid>=off)? tt[tid-off] : -INFINITY;
    __syncthreads();
    tt[tid] = fmaxf(tt[tid], add);
    __syncthreads();
  }
  const float exclm = (tid>0)? tt[tid-1] : -INFINITY;
  #pragma unroll
  for (int i=0;i<8;++i){
    M_out[h*S_LEN+base+i] = fmaxf(exclm, mloc[i]);
    m_out[h*S_LEN+base+i] = mval[i];
  }
}

// ---- Kernel C: 64q tiles, 8 waves (sq x qh), dbuf K/V, 2-round epilogue ---
// Grid (8 heads, 32 q-tiles LPT). L2 staged traffic halved vs r9 (64 q rows
// share each 64KB K/V tile). 1 block/CU -> LDS double-buffer (128KB) hides
// stage latency under compute (no co-resident block to rely on).
__global__ __launch_bounds__(512, 2) void mlstm_mfma8(
    const ushort* __restrict__ qb, const ushort* __restrict__ kb,
    const ushort* __restrict__ vt,
    const float* __restrict__ csb, const float* __restrict__ Mxb,
    const float* __restrict__ mbb,
    const float* __restrict__ nw, float* __restrict__ out){
  const int h = blockIdx.x;
  const int qt = 31 - blockIdx.y;            // LPT: biggest q-tile first
  const int tid = threadIdx.x, l = tid & 63;
  const int w = tid >> 6;                    // 0..7
  const int sq = w & 3, qh = w >> 2;
  const int l31 = l & 31, l15 = l & 15, hi = l >> 5;

  __shared__ __align__(16) float UNI[32768];     // 128 KB: K/V dbuf; Part union
  __shared__ float MB[2][128];
  __shared__ float rsL[4][32];
  ushort* KV = (ushort*)UNI;
  // buffer b: K at b*32768 (32KB), V at b*32768+16384
  float* Part = UNI;                         // [4 sq][32 q][132]

  const int hS = h*S_LEN;
  const ushort* kbh = kb + h*DH;
  const ushort* vth = vt + (size_t)h*DH*S_LEN;
  const float*  mh  = mbb + hS;
  const int t0 = qt*64;
  const int NT = (t0 + 63)/128 + 1;
  const int tgq = t0 + qh*32 + l31;
  const float Mq = Mxb[hS + tgq];

  bf16x8 qf0,qf1,qf2,qf3,qf4,qf5,qf6,qf7;
  { const ushort* qs = qb + (size_t)tgq*E_DIM + h*DH + hi*8;
    qf0 = *(const bf16x8*)(qs+0);   qf1 = *(const bf16x8*)(qs+16);
    qf2 = *(const bf16x8*)(qs+32);  qf3 = *(const bf16x8*)(qs+48);
    qf4 = *(const bf16x8*)(qs+64);  qf5 = *(const bf16x8*)(qs+80);
    qf6 = *(const bf16x8*)(qs+96);  qf7 = *(const bf16x8*)(qs+112); }

  f32x16 a0 = Z16, a1 = Z16, a2 = Z16, a3 = Z16;
  float rsq = 0.f;

#define STAGE8(ktv, bb) {                                                    \
    ushort* kd_ = KV + (bb)*32768;                                           \
    ushort* vd_ = kd_ + 16384;                                               \
    _Pragma("unroll")                                                        \
    for (int i_=0;i_<4;++i_){                                                \
      const int L_ = tid + i_*512; const int row_ = L_>>4, pc_ = L_&15;      \
      stage16(kbh + (size_t)((ktv)*128+row_)*E_DIM + ((pc_^(row_&15))<<3),   \
              kd_ + (size_t)L_*8); }                                         \
    _Pragma("unroll")                                                        \
    for (int i_=0;i_<4;++i_){                                                \
      const int L_ = tid + i_*512; const int d_ = L_>>4, pc_ = L_&15;        \
      stage16(vth + (size_t)d_*S_LEN + (ktv)*128 + ((pc_^(d_&15))<<3),       \
              vd_ + (size_t)L_*8); }                                         \
    if (tid < 32)                                                            \
      stage16((const ushort*)(mh + (ktv)*128) + tid*8,                       \
              (ushort*)&MB[bb][0] + tid*8); }

  STAGE8(0, 0);
  int buf = 0;
  for (int kt=0; kt<NT; ++kt){
    __syncthreads();                         // stage(kt) landed; prev reads done
    if (kt+1 < NT){ STAGE8(kt+1, buf^1); }   // flies under compute(kt)

    const ushort* Kc = KV + buf*32768;
    const ushort* Vc = Kc + 16384;
    const float*  Mc = &MB[buf][0];

    const ushort* kbase = Kc + (size_t)(sq*32 + l31)*128;
    f32x16 cc = Z16;
    { bf16x8 ka;
      ka = *(const bf16x8*)(kbase + (((0*2+hi)^l15)<<3)); cc = MFMA3216(ka, qf0, cc);
      ka = *(const bf16x8*)(kbase + (((1*2+hi)^l15)<<3)); cc = MFMA3216(ka, qf1, cc);
      ka = *(const bf16x8*)(kbase + (((2*2+hi)^l15)<<3)); cc = MFMA3216(ka, qf2, cc);
      ka = *(const bf16x8*)(kbase + (((3*2+hi)^l15)<<3)); cc = MFMA3216(ka, qf3, cc);
      ka = *(const bf16x8*)(kbase + (((4*2+hi)^l15)<<3)); cc = MFMA3216(ka, qf4, cc);
      ka = *(const bf16x8*)(kbase + (((5*2+hi)^l15)<<3)); cc = MFMA3216(ka, qf5, cc);
      ka = *(const bf16x8*)(kbase + (((6*2+hi)^l15)<<3)); cc = MFMA3216(ka, qf6, cc);
      ka = *(const bf16x8*)(kbase + (((7*2+hi)^l15)<<3)); cc = MFMA3216(ka, qf7, cc); }

    bf16x8 fE, fO;
    {
      const int sb_ = kt*128 + sq*32 + 4*hi;
      const f32x4 mA_ = *(const f32x4*)&Mc[sq*32 +  0 + 4*hi];
      const f32x4 mB_ = *(const f32x4*)&Mc[sq*32 +  8 + 4*hi];
      const f32x4 mC_ = *(const f32x4*)&Mc[sq*32 + 16 + 4*hi];
      const f32x4 mD_ = *(const f32x4*)&Mc[sq*32 + 24 + 4*hi];
      float p0  = (sb_+0  <= tgq) ? cc[0] *__expf(mA_[0]-Mq) : 0.f;
      float p1  = (sb_+1  <= tgq) ? cc[1] *__expf(mA_[1]-Mq) : 0.f;
      float p2  = (sb_+2  <= tgq) ? cc[2] *__expf(mA_[2]-Mq) : 0.f;
      float p3  = (sb_+3  <= tgq) ? cc[3] *__expf(mA_[3]-Mq) : 0.f;
      float p4  = (sb_+8  <= tgq) ? cc[4] *__expf(mB_[0]-Mq) : 0.f;
      float p5  = (sb_+9  <= tgq) ? cc[5] *__expf(mB_[1]-Mq) : 0.f;
      float p6  = (sb_+10 <= tgq) ? cc[6] *__expf(mB_[2]-Mq) : 0.f;
      float p7  = (sb_+11 <= tgq) ? cc[7] *__expf(mB_[3]-Mq) : 0.f;
      float p8  = (sb_+16 <= tgq) ? cc[8] *__expf(mC_[0]-Mq) : 0.f;
      float p9  = (sb_+17 <= tgq) ? cc[9] *__expf(mC_[1]-Mq) : 0.f;
      float p10 = (sb_+18 <= tgq) ? cc[10]*__expf(mC_[2]-Mq) : 0.f;
      float p11 = (sb_+19 <= tgq) ? cc[11]*__expf(mC_[3]-Mq) : 0.f;
      float p12 = (sb_+24 <= tgq) ? cc[12]*__expf(mD_[0]-Mq) : 0.f;
      float p13 = (sb_+25 <= tgq) ? cc[13]*__expf(mD_[1]-Mq) : 0.f;
      float p14 = (sb_+26 <= tgq) ? cc[14]*__expf(mD_[2]-Mq) : 0.f;
      float p15 = (sb_+27 <= tgq) ? cc[15]*__expf(mD_[3]-Mq) : 0.f;
      rsq += ((p0+p1)+(p2+p3))+((p4+p5)+(p6+p7))
           + ((p8+p9)+(p10+p11))+((p12+p13)+(p14+p15));
      unsigned A0_=cvtpk(p0,p1),  A1_=cvtpk(p2,p3);
      unsigned B0_=cvtpk(p4,p5),  B1_=cvtpk(p6,p7);
      unsigned C0_=cvtpk(p8,p9),  C1_=cvtpk(p10,p11);
      unsigned D0_=cvtpk(p12,p13),D1_=cvtpk(p14,p15);
      unsigned A0x_=(unsigned)__shfl_xor((int)A0_,32,64);
      unsigned B0x_=(unsigned)__shfl_xor((int)B0_,32,64);
      unsigned A1x_=(unsigned)__shfl_xor((int)A1_,32,64);
      unsigned B1x_=(unsigned)__shfl_xor((int)B1_,32,64);
      unsigned C0x_=(unsigned)__shfl_xor((int)C0_,32,64);
      unsigned D0x_=(unsigned)__shfl_xor((int)D0_,32,64);
      unsigned C1x_=(unsigned)__shfl_xor((int)C1_,32,64);
      unsigned D1x_=(unsigned)__shfl_xor((int)D1_,32,64);
      { unsigned* u_ = (unsigned*)&fE;
        u_[0] = hi ? B0x_ : A0_;  u_[1] = hi ? B1x_ : A1_;
        u_[2] = hi ? B0_  : A0x_; u_[3] = hi ? B1_  : A1x_; }
      { unsigned* u_ = (unsigned*)&fO;
        u_[0] = hi ? D0x_ : C0_;  u_[1] = hi ? D1x_ : C1_;
        u_[2] = hi ? D0_  : C0x_; u_[3] = hi ? D1_  : C1x_; }
    }

#define LV8(dt, cs) (*(const bf16x8*)(Vc + (size_t)((dt)*32+l31)*128 + (((cs)^l15)<<3)))
    a0 = MFMA3216(fE, LV8(0, sq*4 + 0 + hi), a0);
    a1 = MFMA3216(fE, LV8(1, sq*4 + 0 + hi), a1);
    a2 = MFMA3216(fE, LV8(2, sq*4 + 0 + hi), a2);
    a3 = MFMA3216(fE, LV8(3, sq*4 + 0 + hi), a3);
    a0 = MFMA3216(fO, LV8(0, sq*4 + 2 + hi), a0);
    a1 = MFMA3216(fO, LV8(1, sq*4 + 2 + hi), a1);
    a2 = MFMA3216(fO, LV8(2, sq*4 + 2 + hi), a2);
    a3 = MFMA3216(fO, LV8(3, sq*4 + 2 + hi), a3);
#undef LV8
    buf ^= 1;
  }

  // -------- epilogue: two rounds (qh=0 then qh=1) via shared Part ----------
  #pragma unroll
  for (int r2=0; r2<2; ++r2){
    __syncthreads();                 // K/V reads done (r2=0) / prev Part reads (r2=1)
    if (qh == r2){
      #pragma unroll
      for (int r=0;r<16;++r){
        const int qrow = CROW(r) + 4*hi;
        float* pr = Part + (size_t)(sq*32 + qrow)*132 + l31;
        pr[0]  = a0[r];
        pr[32] = a1[r];
        pr[64] = a2[r];
        pr[96] = a3[r];
      }
      float rs2 = rsq + __shfl_xor(rsq, 32, 64);
      if (l < 32) rsL[sq][l31] = rs2;
    }
    __syncthreads();
    {
      const int q = tid >> 4;        // 0..31
      const int dg = tid & 15;       // 0..15 -> d = dg*8 .. +7
      f32x4 osA={0.f,0.f,0.f,0.f}, osB=osA;
      #pragma unroll
      for (int w2=0; w2<4; ++w2){
        const float* pb = Part + (size_t)(w2*32 + q)*132 + dg*8;
        osA += *(const f32x4*)(pb+0);
        osB += *(const f32x4*)(pb+4);
      }
      const float rstot = rsL[0][q]+rsL[1][q]+rsL[2][q]+rsL[3][q];
      const int tq = t0 + r2*32 + q;
      const float en = __expf(-(csb[hS+tq] + Mxb[hS+tq]));
      const float iv = 1.f/(fmaxf(fabsf(rstot), en) + 1e-6f);
      f32x4 hA, hB;
      hA[0]=osA[0]*iv; hA[1]=osA[1]*iv; hA[2]=osA[2]*iv; hA[3]=osA[3]*iv;
      hB[0]=osB[0]*iv; hB[1]=osB[1]*iv; hB[2]=osB[2]*iv; hB[3]=osB[3]*iv;
      float s1 = (hA[0]+hA[1]+hA[2]+hA[3]) + (hB[0]+hB[1]+hB[2]+hB[3]);
      float s2 = (hA[0]*hA[0]+hA[1]*hA[1]+hA[2]*hA[2]+hA[3]*hA[3])
               + (hB[0]*hB[0]+hB[1]*hB[1]+hB[2]*hB[2]+hB[3]*hB[3]);
      s1 += __shfl_xor(s1, 1, 64);  s2 += __shfl_xor(s2, 1, 64);
      s1 += __shfl_xor(s1, 2, 64);  s2 += __shfl_xor(s2, 2, 64);
      s1 += __shfl_xor(s1, 4, 64);  s2 += __shfl_xor(s2, 4, 64);
      s1 += __shfl_xor(s1, 8, 64);  s2 += __shfl_xor(s2, 8, 64);
      const float mean = s1*(1.f/128.f);
      const float var  = s2*(1.f/128.f) - mean*mean;
      const float rstd = rsqrtf(var + 1e-5f);
      const float* nb = nw + h*DH + dg*8;
      const f32x4 n0 = *(const f32x4*)(nb+0);
      const f32x4 n1 = *(const f32x4*)(nb+4);
      float* ob = out + (size_t)tq*E_DIM + h*DH + dg*8;
      f32x4 oA, oB;
      oA[0]=(hA[0]-mean)*rstd*n0[0]; oA[1]=(hA[1]-mean)*rstd*n0[1];
      oA[2]=(hA[2]-mean)*rstd*n0[2]; oA[3]=(hA[3]-mean)*rstd*n0[3];
      oB[0]=(hB[0]-mean)*rstd*n1[0]; oB[1]=(hB[1]-mean)*rstd*n1[1];
      oB[2]=(hB[2]-mean)*rstd*n1[2]; oB[3]=(hB[3]-mean)*rstd*n1[3];
      *(f32x4*)(ob+0) = oA;
      *(f32x4*)(ob+4) = oB;
    }
  }
}

extern "C" void kernel_launch(void* const* d_in, const int* in_sizes, int n_in,
                              void* d_out, int out_size, void* d_ws, size_t ws_size,
                              hipStream_t stream) {
  const float* q   = (const float*)d_in[0];
  const float* k   = (const float*)d_in[1];
  const float* v   = (const float*)d_in[2];
  const float* igw = (const float*)d_in[3];
  const float* igb = (const float*)d_in[4];
  const float* fgw = (const float*)d_in[5];
  const float* fgb = (const float*)d_in[6];
  const float* nw  = (const float*)d_in[7];
  float* outp = (float*)d_out;

  float* ws  = (float*)d_ws;
  float* ig  = ws;                 // NH*S
  float* lsf = ws + 1*NHEAD*S_LEN;
  float* csb = ws + 2*NHEAD*S_LEN;
  float* Mb  = ws + 3*NHEAD*S_LEN;
  float* mbf = ws + 4*NHEAD*S_LEN;
  ushort* qbb = (ushort*)(ws + 5*NHEAD*S_LEN);          // S*E bf16 (scaled)
  ushort* kbb = qbb + (size_t)S_LEN*E_DIM;              // S*E bf16
  ushort* vtb = kbb + (size_t)S_LEN*E_DIM;              // E*S bf16 (per-head V^T)

  gates_qk<<<S_LEN/4, 256, 0, stream>>>(q, k, v, igw, igb, fgw, fgb,
                                        ig, lsf, qbb, kbb, vtb);
  scan_kernel<<<NHEAD, 256, 0, stream>>>(ig, lsf, csb, Mb, mbf);
  mlstm_mfma8<<<dim3(NHEAD, 32), 512, 0, stream>>>(qbb, kbb, vtb, csb, Mb, mbf, nw, outp);
}